// Round 13
// baseline (293.248 us; speedup 1.0000x reference)
//
#include <hip/hip_runtime.h>

// FastFFN: hierarchical-gated 8-leaf GLU MLP.
//   mixture[t][l] = cn[l>>2]*cn[l>>1]*cn[l]
//   H[t][l*512+h] = (x.w1a + b1a)*(x.w1b + b1b)*mixture   (bf16)
//   Y = H @ concat(w2) + sum_l mixture_l * b2_l           (fp32)
// R13: gemm1 switched to mfma_f32_32x32x16_bf16 (16 instrs/iter @8.07cyc =
// 129 cyc matrix-pipe vs 32 @4.85 = 155; measured ceiling 2495 vs 2176 TF).
// Same LDS bytes, same acc VGPR count, same 64x64 wave tile (2x2 of 32x32).
// C/D map (m74/m101): col=lane&31, row=(reg&3)+8*(reg>>2)+4*(lane>>5).
// Everything else frozen at R12 (best: 274.4 us).

typedef unsigned short u16;
typedef __attribute__((ext_vector_type(8))) short bf16x8;
typedef __attribute__((ext_vector_type(8))) unsigned short u16x8;
typedef __attribute__((ext_vector_type(4))) float f32x4;
typedef __attribute__((ext_vector_type(16))) float f32x16;

__device__ __forceinline__ u16 f2bf(float f) {
  unsigned int u = __builtin_bit_cast(unsigned int, f);
  u += 0x7FFFu + ((u >> 16) & 1u);  // RNE
  return (u16)(u >> 16);
}

__device__ __forceinline__ void gload16(const void* g, void* l) {
  __builtin_amdgcn_global_load_lds(
      (const __attribute__((address_space(1))) unsigned int*)g,
      (__attribute__((address_space(3))) unsigned int*)l, 16, 0, 0);
}

__device__ __forceinline__ f32x4 MFMA(bf16x8 a, bf16x8 b, f32x4 c) {
  return __builtin_amdgcn_mfma_f32_16x16x32_bf16(a, b, c, 0, 0, 0);
}
__device__ __forceinline__ f32x16 MFMA32(bf16x8 a, bf16x8 b, f32x16 c) {
  return __builtin_amdgcn_mfma_f32_32x32x16_bf16(a, b, c, 0, 0, 0);
}

#define BARX()                              \
  do {                                      \
    __builtin_amdgcn_sched_barrier(0);      \
    __builtin_amdgcn_s_barrier();           \
    __builtin_amdgcn_sched_barrier(0);      \
  } while (0)

#define VMC(n)                                             \
  do {                                                     \
    __builtin_amdgcn_sched_barrier(0);                     \
    asm volatile("s_waitcnt vmcnt(" #n ")" ::: "memory");  \
    __builtin_amdgcn_sched_barrier(0);                     \
  } while (0)

// -------- fused gate + cast: mixture (8192x8) and Xb (bf16) in one x pass ----
__global__ void k_gatecast(const float* __restrict__ x, const float* __restrict__ nk,
                           const float* __restrict__ nb, float* __restrict__ mix,
                           u16* __restrict__ xb) {
  int token = blockIdx.x * 4 + (threadIdx.x >> 6);
  int lane = threadIdx.x & 63;
  const float* xr = x + (size_t)token * 1024;
  u16* xbr = xb + (size_t)token * 1024;
  float a0 = 0.f, a1 = 0.f, a2 = 0.f, a3 = 0.f;
#pragma unroll
  for (int j = 0; j < 2; ++j) {
    int base = j * 512 + lane * 8;
    float4 p0 = *(const float4*)&xr[base];
    float4 p1 = *(const float4*)&xr[base + 4];
    float v[8] = {p0.x, p0.y, p0.z, p0.w, p1.x, p1.y, p1.z, p1.w};
    u16x8 o;
#pragma unroll
    for (int t = 0; t < 8; ++t) {
      const float* nkd = nk + (size_t)(base + t) * 7;
      a0 = fmaf(v[t], nkd[0], a0);
      a1 = fmaf(v[t], nkd[1], a1);
      a2 = fmaf(v[t], nkd[2], a2);
      a3 = fmaf(v[t], nkd[3], a3);
      o[t] = f2bf(v[t]);
    }
    *(u16x8*)&xbr[base] = o;
  }
#pragma unroll
  for (int off = 32; off >= 1; off >>= 1) {
    a0 += __shfl_xor(a0, off);
    a1 += __shfl_xor(a1, off);
    a2 += __shfl_xor(a2, off);
    a3 += __shfl_xor(a3, off);
  }
  if (lane == 0) {
    float v4[4] = {a0 + nb[0], a1 + nb[1], a2 + nb[2], a3 + nb[3]};
    float cn[8];
#pragma unroll
    for (int i = 0; i < 4; ++i) {
      float s = 1.f / (1.f + expf(-v4[i]));
      cn[2 * i] = s;
      cn[2 * i + 1] = 1.f - s;
    }
    float* mr = mix + (size_t)token * 8;
#pragma unroll
    for (int l = 0; l < 8; ++l) mr[l] = cn[l >> 2] * cn[l >> 1] * cn[l];
  }
}

// ------------- batched transpose+cast: out[(c),(r)] = in[l][r][c] -------------
__global__ void k_transpose_cast(const float* __restrict__ in, u16* __restrict__ out,
                                 int R, int C, long out_rstride, long leaf_base) {
  __shared__ float tile[32][33];
  int l = blockIdx.z;
  int c0 = blockIdx.x * 32, r0 = blockIdx.y * 32;
  const float* inl = in + (size_t)l * R * C;
  int tc = threadIdx.x & 31, tr = threadIdx.x >> 5;  // 0..7
#pragma unroll
  for (int i = 0; i < 4; ++i) {
    int r = tr + i * 8;
    tile[r][tc] = inl[(size_t)(r0 + r) * C + c0 + tc];
  }
  __syncthreads();
  u16* outl = out + (size_t)l * leaf_base;
#pragma unroll
  for (int i = 0; i < 4; ++i) {
    int c = tr + i * 8;
    outl[(size_t)(c0 + c) * out_rstride + r0 + tc] = f2bf(tile[tc][c]);
  }
}

// merged w1a+w1b transpose: z 0..7 -> w1a leaf z; z 8..15 -> w1b leaf z-8.
__global__ void k_transpose_w1(const float* __restrict__ w1a, const float* __restrict__ w1b,
                               u16* __restrict__ WaT, u16* __restrict__ WbT) {
  __shared__ float tile[32][33];
  int z = blockIdx.z;
  int l = z & 7;
  const float* in = (z < 8) ? w1a : w1b;
  u16* out = (z < 8) ? WaT : WbT;
  int c0 = blockIdx.x * 32, r0 = blockIdx.y * 32;  // c over 512, r over 1024
  const float* inl = in + (size_t)l * 1024 * 512;
  int tc = threadIdx.x & 31, tr = threadIdx.x >> 5;
#pragma unroll
  for (int i = 0; i < 4; ++i) {
    int r = tr + i * 8;
    tile[r][tc] = inl[(size_t)(r0 + r) * 512 + c0 + tc];
  }
  __syncthreads();
  u16* outl = out + (size_t)l * 512 * 1024;
#pragma unroll
  for (int i = 0; i < 4; ++i) {
    int c = tr + i * 8;
    outl[(size_t)(c0 + c) * 1024 + r0 + tc] = f2bf(tile[tc][c]);
  }
}

// ---------------- GEMM1: GLU, H = (X@Wa+b1a)*(X@Wb+b1b)*mix ----------------
// X: 8192x1024 bf16 rm; Wa/Wb: 4096x1024 bf16 (NxK); H: 8192x4096 bf16
// grid 2048, 256 thr, BK=32, NT=32, bn-fast-within-XCD. 56 KB LDS (sA 3-slot,
// sBa/sBb 2-slot), 2 blocks/CU, counted vmcnt(2). 32x32x16 MFMA (R13).
__global__ __launch_bounds__(256, 2) void k_glu_gemm(
    const u16* __restrict__ Xb, const u16* __restrict__ Wa, const u16* __restrict__ Wb,
    const float* __restrict__ b1a, const float* __restrict__ b1b,
    const float* __restrict__ mix, u16* __restrict__ H) {
  constexpr int K = 1024, NT = 32;
  __shared__ alignas(16) u16 smem[28672];  // sA 3x4096 @0 | sBa 2x4096 @12288 | sBb 2x4096 @20480
  const int tid = threadIdx.x;
  const int logical = (blockIdx.x & 7) * 256 + (blockIdx.x >> 3);
  const int xcd_chunk = logical >> 8;          // 0..7
  const int i_ = logical & 255;
  const int bn = xcd_chunk * 4 + (i_ & 3);     // bn-local fast (L2 weights)
  const int bm = i_ >> 2;                      // 0..63 slow
  const int m0 = bm * 128, n0 = bn * 128;
  const int wid = tid >> 6, lane = tid & 63;
  const int wm = (wid >> 1) * 64, wn = (wid & 1) * 64;
  const int l32 = lane & 31, kh = lane >> 5;   // 32x32 fragment coords

  const int c0_ = tid, c1_ = tid + 256;
  const int r0_ = c0_ >> 2, s0_ = ((c0_ & 3) ^ ((r0_ >> 1) & 3)) * 8;
  const int r1_ = c1_ >> 2, s1_ = ((c1_ & 3) ^ ((r1_ >> 1) & 3)) * 8;

#define STG_A(v)                                                                    \
  do {                                                                              \
    const int kb = (v) * 32;                                                        \
    u16* dA = smem + ((v) % 3) * 4096;                                              \
    gload16(&Xb[(size_t)(m0 + r0_) * K + kb + s0_], &dA[c0_ * 8]);                  \
    gload16(&Xb[(size_t)(m0 + r1_) * K + kb + s1_], &dA[c1_ * 8]);                  \
  } while (0)
#define STG_BA(v)                                                                   \
  do {                                                                              \
    const int kb = (v) * 32;                                                        \
    u16* dBa = smem + 12288 + ((v) & 1) * 4096;                                     \
    gload16(&Wa[(size_t)(n0 + r0_) * K + kb + s0_], &dBa[c0_ * 8]);                 \
    gload16(&Wa[(size_t)(n0 + r1_) * K + kb + s1_], &dBa[c1_ * 8]);                 \
  } while (0)
#define STG_BB(v)                                                                   \
  do {                                                                              \
    const int kb = (v) * 32;                                                        \
    u16* dBb = smem + 20480 + ((v) & 1) * 4096;                                     \
    gload16(&Wb[(size_t)(n0 + r0_) * K + kb + s0_], &dBb[c0_ * 8]);                 \
    gload16(&Wb[(size_t)(n0 + r1_) * K + kb + s1_], &dBb[c1_ * 8]);                 \
  } while (0)

  f32x16 accA[2][2], accB[2][2];
#pragma unroll
  for (int i = 0; i < 2; ++i)
#pragma unroll
    for (int j = 0; j < 2; ++j) {
      accA[i][j] = (f32x16)0.0f;
      accB[i][j] = (f32x16)0.0f;
    }

  // fragment read: row = base + l32 (base mult of 32) -> (row>>1)&3 = (l32>>1)&3.
  // k-base for kstep ks = ks*16 + kh*8 -> 16B slot = ks*2+kh; XOR with row bits.
  const int rsw = (l32 >> 1) & 3;
  const int sl0 = ((0 + kh) ^ rsw) * 8;   // ks=0
  const int sl1 = ((2 + kh) ^ rsw) * 8;   // ks=1

  // prologue (issue order fixes vmcnt ledger): Ba0, Bb0, A0, A1
  STG_BA(0); STG_BB(0); STG_A(0); STG_A(1);

  for (int u = 0; u < NT; ++u) {
    // entry: need Ba(u),Bb(u),A(u) complete; newest-allowed = A(u+1) (2 loads)
    if (u + 1 < NT) { VMC(2); } else { VMC(0); }
    BARX();
    if (u + 1 < NT) { STG_BA(u + 1); STG_BB(u + 1); }
    if (u + 2 < NT) STG_A(u + 2);
    __builtin_amdgcn_sched_barrier(0);
    const u16* A_  = smem + (u % 3) * 4096;
    const u16* Ba_ = smem + 12288 + (u & 1) * 4096;
    const u16* Bb_ = smem + 20480 + (u & 1) * 4096;
    bf16x8 a32[2][2], ba32[2][2], bb32[2][2];   // [blk][ks]
#pragma unroll
    for (int b = 0; b < 2; ++b) {
      int ra = (wm + b * 32 + l32) * 32;
      int rb = (wn + b * 32 + l32) * 32;
      a32[b][0]  = *(const bf16x8*)&A_[ra + sl0];
      a32[b][1]  = *(const bf16x8*)&A_[ra + sl1];
      ba32[b][0] = *(const bf16x8*)&Ba_[rb + sl0];
      ba32[b][1] = *(const bf16x8*)&Ba_[rb + sl1];
      bb32[b][0] = *(const bf16x8*)&Bb_[rb + sl0];
      bb32[b][1] = *(const bf16x8*)&Bb_[rb + sl1];
    }
    __builtin_amdgcn_s_setprio(1);
#pragma unroll
    for (int i = 0; i < 2; ++i)
#pragma unroll
      for (int j = 0; j < 2; ++j) {
        accA[i][j] = MFMA32(a32[i][0], ba32[j][0], accA[i][j]);
        accA[i][j] = MFMA32(a32[i][1], ba32[j][1], accA[i][j]);
        accB[i][j] = MFMA32(a32[i][0], bb32[j][0], accB[i][j]);
        accB[i][j] = MFMA32(a32[i][1], bb32[j][1], accB[i][j]);
      }
    __builtin_amdgcn_s_setprio(0);
  }
#undef STG_A
#undef STG_BA
#undef STG_BB

  // ---- epilogue: GLU -> LDS [128][128] bf16 -> coalesced 16B stores ----
  // 32x32 C/D map: col = l32, row = (r&3) + 8*(r>>2) + 4*kh   (r in [0,16))
  BARX();   // all waves done with K-loop LDS
  const int leaf = n0 >> 9;
  const float* b1al = b1a + (leaf << 9);
  const float* b1bl = b1b + (leaf << 9);
  u16* hs = smem;  // 32 KB tile
#pragma unroll
  for (int rb = 0; rb < 2; ++rb)
#pragma unroll
    for (int r = 0; r < 16; ++r) {
      int row_l = wm + rb * 32 + (r & 3) + 8 * (r >> 2) + 4 * kh;
      float mv = mix[(size_t)(m0 + row_l) * 8 + leaf];
#pragma unroll
      for (int cb = 0; cb < 2; ++cb) {
        int col_l = wn + cb * 32 + l32;
        int hc = (n0 + col_l) & 511;
        float va = accA[rb][cb][r] + b1al[hc];
        float vb = accB[rb][cb][r] + b1bl[hc];
        hs[row_l * 128 + col_l] = f2bf(va * vb * mv);
      }
    }
  BARX();
#pragma unroll
  for (int j = 0; j < 8; ++j) {
    int idx = j * 256 + tid;        // 2048 chunks of 16B
    int row_l = idx >> 4;           // 16 chunks per row
    int cc = (idx & 15) * 8;
    *(u16x8*)&H[(size_t)(m0 + row_l) * 4096 + n0 + cc] =
        *(const u16x8*)&hs[row_l * 128 + cc];
  }
}

// ---------------- GEMM2 (split-K=2): Y-partials over K-halves ----------------
// H: 8192x4096 bf16; W2T: 1024x4096 bf16 (NxK); out/P1: 8192x1024 fp32
// grid 1024, 256 thr, BK=32, LDS 40 KB (sA 3-slot, sB 2-slot), 4 blocks/CU.
// kc0 -> out (+ mix.b2 bias); kc1 -> P1. LDS full-line epilogue. (frozen R12)
__global__ __launch_bounds__(256, 4) void k_gemm2s(
    const u16* __restrict__ Hm, const u16* __restrict__ W2T,
    const float* __restrict__ b2, const float* __restrict__ mix,
    float* __restrict__ out, float* __restrict__ P1) {
  constexpr int K = 4096, KH = 2048, NT = KH / 32;  // 64
  __shared__ alignas(16) u16 smem[20480];  // sA 3x4096 @0 | sB 2x4096 @12288
  const int tid = threadIdx.x;
  const int logical = (blockIdx.x & 7) * 128 + (blockIdx.x >> 3);
  const int xcd_chunk = logical >> 7;          // 0..7
  const int i_ = logical & 127;
  const int kc = i_ >> 6;                      // 0/1 (both halves same XCD)
  const int bn = i_ & 7;
  const int bm = xcd_chunk * 8 + ((i_ >> 3) & 7);
  const int m0 = bm * 128, n0 = bn * 128;
  const size_t kbase = (size_t)kc * KH;
  const int wid = tid >> 6, lane = tid & 63;
  const int wm = (wid >> 1) * 64, wn = (wid & 1) * 64;
  const int fr = lane & 15, fk = lane >> 4;

  const int c0_ = tid, c1_ = tid + 256;
  const int r0_ = c0_ >> 2, s0_ = ((c0_ & 3) ^ ((r0_ >> 1) & 3)) * 8;
  const int r1_ = c1_ >> 2, s1_ = ((c1_ & 3) ^ ((r1_ >> 1) & 3)) * 8;

#define STG2_A(v)                                                                     \
  do {                                                                                \
    const int kb = (v) * 32;                                                          \
    u16* dA = smem + ((v) % 3) * 4096;                                                \
    gload16(&Hm[(size_t)(m0 + r0_) * K + kbase + kb + s0_], &dA[c0_ * 8]);            \
    gload16(&Hm[(size_t)(m0 + r1_) * K + kbase + kb + s1_], &dA[c1_ * 8]);            \
  } while (0)
#define STG2_B(v)                                                                     \
  do {                                                                                \
    const int kb = (v) * 32;                                                          \
    u16* dB = smem + 12288 + ((v) & 1) * 4096;                                        \
    gload16(&W2T[(size_t)(n0 + r0_) * K + kbase + kb + s0_], &dB[c0_ * 8]);           \
    gload16(&W2T[(size_t)(n0 + r1_) * K + kbase + kb + s1_], &dB[c1_ * 8]);           \
  } while (0)

  f32x4 acc[4][4];
#pragma unroll
  for (int i = 0; i < 4; ++i)
#pragma unroll
    for (int j = 0; j < 4; ++j) acc[i][j] = (f32x4)0.0f;

  const int slot_ = (fk ^ ((fr >> 1) & 3)) * 8;

  // prologue (issue order): B0, A0, A1
  STG2_B(0); STG2_A(0); STG2_A(1);

  for (int u = 0; u < NT; ++u) {
    if (u + 1 < NT) { VMC(2); } else { VMC(0); }
    BARX();
    if (u + 1 < NT) STG2_B(u + 1);
    if (u + 2 < NT) STG2_A(u + 2);
    __builtin_amdgcn_sched_barrier(0);
    const u16* A_ = smem + (u % 3) * 4096;
    const u16* B_ = smem + 12288 + (u & 1) * 4096;
    bf16x8 a_[4], b_[4];
#pragma unroll
    for (int i = 0; i < 4; ++i) {
      a_[i] = *(const bf16x8*)&A_[(wm + i * 16 + fr) * 32 + slot_];
      b_[i] = *(const bf16x8*)&B_[(wn + i * 16 + fr) * 32 + slot_];
    }
    __builtin_amdgcn_s_setprio(1);
#pragma unroll
    for (int i = 0; i < 4; ++i)
#pragma unroll
      for (int j = 0; j < 4; ++j)
        acc[i][j] = MFMA(a_[i], b_[j], acc[i][j]);
    __builtin_amdgcn_s_setprio(0);
  }
#undef STG2_A
#undef STG2_B

  // ---- epilogue: two 64-row passes through LDS, full-line stores ----
  float* dst = (kc == 0) ? out : P1;
  float* os = (float*)smem;                 // [64][128] f32 (32 KB)
  const int myhalf = wid >> 1;              // waves 0,1 -> rows 0..63; 2,3 -> 64..127
#pragma unroll
  for (int half = 0; half < 2; ++half) {
    BARX();
    if (myhalf == half) {
#pragma unroll
      for (int nf = 0; nf < 4; ++nf) {
        int col_l = wn + nf * 16 + fr;
        float bc[8];
        if (kc == 0) {
#pragma unroll
          for (int l = 0; l < 8; ++l) bc[l] = b2[l * 1024 + n0 + col_l];
        }
#pragma unroll
        for (int mf = 0; mf < 4; ++mf)
#pragma unroll
          for (int r = 0; r < 4; ++r) {
            int row_lh = mf * 16 + fk * 4 + r;   // 0..63 within half
            float v = acc[mf][nf][r];
            if (kc == 0) {
              const float* mr = mix + (size_t)(m0 + half * 64 + row_lh) * 8;
              float bias = 0.f;
#pragma unroll
              for (int l = 0; l < 8; ++l) bias = fmaf(mr[l], bc[l], bias);
              v += bias;
            }
            os[row_lh * 128 + col_l] = v;
          }
      }
    }
    BARX();
#pragma unroll
    for (int j = 0; j < 8; ++j) {
      int idx = j * 256 + tid;      // 2048 chunks of 16B
      int row_lh = idx >> 5;        // 32 chunks per row
      int cc = (idx & 31) * 4;
      *(float4*)&dst[(size_t)(m0 + half * 64 + row_lh) * 1024 + n0 + cc] =
          *(const float4*)&os[row_lh * 128 + cc];
    }
  }
}

// ---------------- out += P1 (float4, 96 MB traffic) ----------------
__global__ void k_add(float* __restrict__ out, const float* __restrict__ P1) {
  size_t i = (size_t)blockIdx.x * 256 + threadIdx.x;
  float4 a = ((const float4*)out)[i];
  float4 b = ((const float4*)P1)[i];
  a.x += b.x; a.y += b.y; a.z += b.z; a.w += b.w;
  ((float4*)out)[i] = a;
}

extern "C" void kernel_launch(void* const* d_in, const int* in_sizes, int n_in,
                              void* d_out, int out_size, void* d_ws, size_t ws_size,
                              hipStream_t stream) {
  const float* x   = (const float*)d_in[0];
  const float* nk  = (const float*)d_in[1];
  const float* nb  = (const float*)d_in[2];
  const float* w1a = (const float*)d_in[3];
  const float* w1b = (const float*)d_in[4];
  const float* b1a = (const float*)d_in[5];
  const float* b1b = (const float*)d_in[6];
  const float* w2  = (const float*)d_in[7];
  const float* b2  = (const float*)d_in[8];
  float* out = (float*)d_out;

  char* ws = (char*)d_ws;
  // layout: mixture | Xbf | W1aT | W1bT | W2T | H   (~109.3 MB)
  // After gemm1, Xb+WaT+WbT (32.75 MB) are dead; P1 (32 MB) reuses
  // [262144, 262144+33554432) which ends exactly at W2T's start.
  float* mix = (float*)ws;                                   // 262144 B
  u16* Xb  = (u16*)(ws + 262144);                            // 16777216 B
  u16* WaT = (u16*)(ws + 262144 + 16777216);                 // 8388608 B
  u16* WbT = (u16*)(ws + 262144 + 16777216 + 8388608);       // 8388608 B
  u16* W2T = (u16*)(ws + 262144 + 16777216 + 2 * 8388608);   // 8388608 B
  u16* Hs  = (u16*)(ws + 262144 + 16777216 + 3 * 8388608);   // 67108864 B
  float* P1 = (float*)(ws + 262144);                         // 33554432 B (reclaim)

  k_gatecast<<<2048, 256, 0, stream>>>(x, nk, nb, mix, Xb);
  // w1a/w1b[l][d][h] -> W{a,b}T[(l*512+h)*1024 + d]  (merged, z=16)
  k_transpose_w1<<<dim3(16, 32, 16), 256, 0, stream>>>(w1a, w1b, WaT, WbT);
  // w2[l][h][dout] -> W2T[dout*4096 + l*512 + h]
  k_transpose_cast<<<dim3(32, 16, 8), 256, 0, stream>>>(w2, W2T, 512, 1024, 4096L, 512L);
  k_glu_gemm<<<2048, 256, 0, stream>>>(Xb, WaT, WbT, b1a, b1b, mix, Hs);
  k_gemm2s<<<1024, 256, 0, stream>>>(Hs, W2T, b2, mix, out, P1);
  k_add<<<8192, 256, 0, stream>>>(out, P1);
}

// Round 14
// 271.937 us; speedup vs baseline: 1.0784x; 1.0784x over previous
//
#include <hip/hip_runtime.h>

// FastFFN: hierarchical-gated 8-leaf GLU MLP.
//   mixture[t][l] = cn[l>>2]*cn[l>>1]*cn[l]
//   H[t][l*512+h] = (x.w1a + b1a)*(x.w1b + b1b)*mixture   (bf16)
//   Y = H @ concat(w2) + sum_l mixture_l * b2_l           (fp32)
// R14: revert R13's 32x32 MFMA (bank-conflict regression: BK=32 rows are 4
// slots -> 4-way conflict inherent). gemm1 = R12 16x16 kernel (measured at
// ~86% of its LDS-read-pipe roofline). Single delta: all three weight
// transposes merged into one launch (k_transpose_all, 1-D decode).

typedef unsigned short u16;
typedef __attribute__((ext_vector_type(8))) short bf16x8;
typedef __attribute__((ext_vector_type(8))) unsigned short u16x8;
typedef __attribute__((ext_vector_type(4))) float f32x4;

__device__ __forceinline__ u16 f2bf(float f) {
  unsigned int u = __builtin_bit_cast(unsigned int, f);
  u += 0x7FFFu + ((u >> 16) & 1u);  // RNE
  return (u16)(u >> 16);
}

__device__ __forceinline__ void gload16(const void* g, void* l) {
  __builtin_amdgcn_global_load_lds(
      (const __attribute__((address_space(1))) unsigned int*)g,
      (__attribute__((address_space(3))) unsigned int*)l, 16, 0, 0);
}

__device__ __forceinline__ f32x4 MFMA(bf16x8 a, bf16x8 b, f32x4 c) {
  return __builtin_amdgcn_mfma_f32_16x16x32_bf16(a, b, c, 0, 0, 0);
}

#define BARX()                              \
  do {                                      \
    __builtin_amdgcn_sched_barrier(0);      \
    __builtin_amdgcn_s_barrier();           \
    __builtin_amdgcn_sched_barrier(0);      \
  } while (0)

#define VMC(n)                                             \
  do {                                                     \
    __builtin_amdgcn_sched_barrier(0);                     \
    asm volatile("s_waitcnt vmcnt(" #n ")" ::: "memory");  \
    __builtin_amdgcn_sched_barrier(0);                     \
  } while (0)

// -------- fused gate + cast: mixture (8192x8) and Xb (bf16) in one x pass ----
__global__ void k_gatecast(const float* __restrict__ x, const float* __restrict__ nk,
                           const float* __restrict__ nb, float* __restrict__ mix,
                           u16* __restrict__ xb) {
  int token = blockIdx.x * 4 + (threadIdx.x >> 6);
  int lane = threadIdx.x & 63;
  const float* xr = x + (size_t)token * 1024;
  u16* xbr = xb + (size_t)token * 1024;
  float a0 = 0.f, a1 = 0.f, a2 = 0.f, a3 = 0.f;
#pragma unroll
  for (int j = 0; j < 2; ++j) {
    int base = j * 512 + lane * 8;
    float4 p0 = *(const float4*)&xr[base];
    float4 p1 = *(const float4*)&xr[base + 4];
    float v[8] = {p0.x, p0.y, p0.z, p0.w, p1.x, p1.y, p1.z, p1.w};
    u16x8 o;
#pragma unroll
    for (int t = 0; t < 8; ++t) {
      const float* nkd = nk + (size_t)(base + t) * 7;
      a0 = fmaf(v[t], nkd[0], a0);
      a1 = fmaf(v[t], nkd[1], a1);
      a2 = fmaf(v[t], nkd[2], a2);
      a3 = fmaf(v[t], nkd[3], a3);
      o[t] = f2bf(v[t]);
    }
    *(u16x8*)&xbr[base] = o;
  }
#pragma unroll
  for (int off = 32; off >= 1; off >>= 1) {
    a0 += __shfl_xor(a0, off);
    a1 += __shfl_xor(a1, off);
    a2 += __shfl_xor(a2, off);
    a3 += __shfl_xor(a3, off);
  }
  if (lane == 0) {
    float v4[4] = {a0 + nb[0], a1 + nb[1], a2 + nb[2], a3 + nb[3]};
    float cn[8];
#pragma unroll
    for (int i = 0; i < 4; ++i) {
      float s = 1.f / (1.f + expf(-v4[i]));
      cn[2 * i] = s;
      cn[2 * i + 1] = 1.f - s;
    }
    float* mr = mix + (size_t)token * 8;
#pragma unroll
    for (int l = 0; l < 8; ++l) mr[l] = cn[l >> 2] * cn[l >> 1] * cn[l];
  }
}

// ---- merged transpose+cast for w1a, w1b, w2 in ONE launch (1-D decode) ----
// id < 8192: w1 (z=id>>9: 0..7 w1a leaf z, 8..15 w1b leaf z-8; R=1024,C=512)
// id >= 8192: w2 leaf (id-8192)>>9; R=512, C=1024, out_rstride=4096.
__global__ void k_transpose_all(const float* __restrict__ w1a, const float* __restrict__ w1b,
                                const float* __restrict__ w2, u16* __restrict__ WaT,
                                u16* __restrict__ WbT, u16* __restrict__ W2T) {
  __shared__ float tile[32][33];
  const int id = blockIdx.x;
  const float* in;
  u16* out;
  int C;
  long out_rstride;
  int bx, by;
  if (id < 8192) {
    int z = id >> 9;
    int rem = id & 511;
    bx = rem & 15;          // c over 512
    by = rem >> 4;          // r over 1024
    int l = z & 7;
    in = ((z < 8) ? w1a : w1b) + (size_t)l * 1024 * 512;
    out = ((z < 8) ? WaT : WbT) + (size_t)l * 512 * 1024;
    C = 512;
    out_rstride = 1024;
  } else {
    int id2 = id - 8192;
    int z = id2 >> 9;
    int rem = id2 & 511;
    bx = rem & 31;          // c over 1024
    by = rem >> 5;          // r over 512
    in = w2 + (size_t)z * 512 * 1024;
    out = W2T + (size_t)z * 512;
    C = 1024;
    out_rstride = 4096;
  }
  const int c0 = bx * 32, r0 = by * 32;
  const int tc = threadIdx.x & 31, tr = threadIdx.x >> 5;  // 0..7
#pragma unroll
  for (int i = 0; i < 4; ++i) {
    int r = tr + i * 8;
    tile[r][tc] = in[(size_t)(r0 + r) * C + c0 + tc];
  }
  __syncthreads();
#pragma unroll
  for (int i = 0; i < 4; ++i) {
    int c = tr + i * 8;
    out[(size_t)(c0 + c) * out_rstride + r0 + tc] = f2bf(tile[tc][c]);
  }
}

// ---------------- GEMM1: GLU, H = (X@Wa+b1a)*(X@Wb+b1b)*mix ----------------
// X: 8192x1024 bf16 rm; Wa/Wb: 4096x1024 bf16 (NxK); H: 8192x4096 bf16
// grid 2048, 256 thr, BK=32, NT=32, bn-fast-within-XCD (R9 mapping).
// LDS 56 KB: sA 3-slot (X stream) | sBa/sBb 2-slot. 2 blocks/CU.
// Measured ~86% of LDS-read-pipe roofline (12 ds_read_b128 x 8 waves/iter).
__global__ __launch_bounds__(256, 2) void k_glu_gemm(
    const u16* __restrict__ Xb, const u16* __restrict__ Wa, const u16* __restrict__ Wb,
    const float* __restrict__ b1a, const float* __restrict__ b1b,
    const float* __restrict__ mix, u16* __restrict__ H) {
  constexpr int K = 1024, NT = 32;
  __shared__ alignas(16) u16 smem[28672];  // sA 3x4096 @0 | sBa 2x4096 @12288 | sBb 2x4096 @20480
  const int tid = threadIdx.x;
  const int logical = (blockIdx.x & 7) * 256 + (blockIdx.x >> 3);
  const int xcd_chunk = logical >> 8;          // 0..7
  const int i_ = logical & 255;
  const int bn = xcd_chunk * 4 + (i_ & 3);     // bn-local fast (L2 weights)
  const int bm = i_ >> 2;                      // 0..63 slow
  const int m0 = bm * 128, n0 = bn * 128;
  const int wid = tid >> 6, lane = tid & 63;
  const int wm = (wid >> 1) * 64, wn = (wid & 1) * 64;
  const int fr = lane & 15, fk = lane >> 4;

  const int c0_ = tid, c1_ = tid + 256;
  const int r0_ = c0_ >> 2, s0_ = ((c0_ & 3) ^ ((r0_ >> 1) & 3)) * 8;
  const int r1_ = c1_ >> 2, s1_ = ((c1_ & 3) ^ ((r1_ >> 1) & 3)) * 8;

#define STG_A(v)                                                                    \
  do {                                                                              \
    const int kb = (v) * 32;                                                        \
    u16* dA = smem + ((v) % 3) * 4096;                                              \
    gload16(&Xb[(size_t)(m0 + r0_) * K + kb + s0_], &dA[c0_ * 8]);                  \
    gload16(&Xb[(size_t)(m0 + r1_) * K + kb + s1_], &dA[c1_ * 8]);                  \
  } while (0)
#define STG_BA(v)                                                                   \
  do {                                                                              \
    const int kb = (v) * 32;                                                        \
    u16* dBa = smem + 12288 + ((v) & 1) * 4096;                                     \
    gload16(&Wa[(size_t)(n0 + r0_) * K + kb + s0_], &dBa[c0_ * 8]);                 \
    gload16(&Wa[(size_t)(n0 + r1_) * K + kb + s1_], &dBa[c1_ * 8]);                 \
  } while (0)
#define STG_BB(v)                                                                   \
  do {                                                                              \
    const int kb = (v) * 32;                                                        \
    u16* dBb = smem + 20480 + ((v) & 1) * 4096;                                     \
    gload16(&Wb[(size_t)(n0 + r0_) * K + kb + s0_], &dBb[c0_ * 8]);                 \
    gload16(&Wb[(size_t)(n0 + r1_) * K + kb + s1_], &dBb[c1_ * 8]);                 \
  } while (0)

  f32x4 accA[4][4], accB[4][4];
#pragma unroll
  for (int i = 0; i < 4; ++i)
#pragma unroll
    for (int j = 0; j < 4; ++j) {
      accA[i][j] = (f32x4)0.0f;
      accB[i][j] = (f32x4)0.0f;
    }

  const int slot_ = (fk ^ ((fr >> 1) & 3)) * 8;

  // prologue (issue order fixes vmcnt ledger): Ba0, Bb0, A0, A1
  STG_BA(0); STG_BB(0); STG_A(0); STG_A(1);

  for (int u = 0; u < NT; ++u) {
    // entry: need Ba(u),Bb(u),A(u) complete; newest-allowed = A(u+1) (2 loads)
    if (u + 1 < NT) { VMC(2); } else { VMC(0); }
    BARX();
    if (u + 1 < NT) { STG_BA(u + 1); STG_BB(u + 1); }
    if (u + 2 < NT) STG_A(u + 2);
    __builtin_amdgcn_sched_barrier(0);
    const u16* A_  = smem + (u % 3) * 4096;
    const u16* Ba_ = smem + 12288 + (u & 1) * 4096;
    const u16* Bb_ = smem + 20480 + (u & 1) * 4096;
    bf16x8 a_[4], ba_[4], bb_[4];
#pragma unroll
    for (int i = 0; i < 4; ++i) {
      a_[i]  = *(const bf16x8*)&A_[(wm + i * 16 + fr) * 32 + slot_];
      ba_[i] = *(const bf16x8*)&Ba_[(wn + i * 16 + fr) * 32 + slot_];
      bb_[i] = *(const bf16x8*)&Bb_[(wn + i * 16 + fr) * 32 + slot_];
    }
    __builtin_amdgcn_s_setprio(1);
#pragma unroll
    for (int i = 0; i < 4; ++i)
#pragma unroll
      for (int j = 0; j < 4; ++j) {
        accA[i][j] = MFMA(a_[i], ba_[j], accA[i][j]);
        accB[i][j] = MFMA(a_[i], bb_[j], accB[i][j]);
      }
    __builtin_amdgcn_s_setprio(0);
  }
#undef STG_A
#undef STG_BA
#undef STG_BB

  // ---- epilogue: GLU -> LDS [128][128] bf16 -> coalesced 16B stores ----
  BARX();   // all waves done with K-loop LDS
  const int leaf = n0 >> 9;
  const float* b1al = b1a + (leaf << 9);
  const float* b1bl = b1b + (leaf << 9);
  u16* hs = smem;  // 32 KB tile
#pragma unroll
  for (int mf = 0; mf < 4; ++mf)
#pragma unroll
    for (int r = 0; r < 4; ++r) {
      int row_l = wm + mf * 16 + fk * 4 + r;
      float mv = mix[(size_t)(m0 + row_l) * 8 + leaf];
#pragma unroll
      for (int nf = 0; nf < 4; ++nf) {
        int col_l = wn + nf * 16 + fr;
        int hc = (n0 + col_l) & 511;
        float va = accA[mf][nf][r] + b1al[hc];
        float vb = accB[mf][nf][r] + b1bl[hc];
        hs[row_l * 128 + col_l] = f2bf(va * vb * mv);
      }
    }
  BARX();
#pragma unroll
  for (int j = 0; j < 8; ++j) {
    int idx = j * 256 + tid;        // 2048 chunks of 16B
    int row_l = idx >> 4;           // 16 chunks per row
    int cc = (idx & 15) * 8;
    *(u16x8*)&H[(size_t)(m0 + row_l) * 4096 + n0 + cc] =
        *(const u16x8*)&hs[row_l * 128 + cc];
  }
}

// ---------------- GEMM2 (split-K=2): Y-partials over K-halves ----------------
// H: 8192x4096 bf16; W2T: 1024x4096 bf16 (NxK); out/P1: 8192x1024 fp32
// grid 1024, 256 thr, BK=32, LDS 40 KB (sA 3-slot, sB 2-slot), 4 blocks/CU.
// kc0 -> out (+ mix.b2 bias); kc1 -> P1. LDS full-line epilogue. (frozen R12)
__global__ __launch_bounds__(256, 4) void k_gemm2s(
    const u16* __restrict__ Hm, const u16* __restrict__ W2T,
    const float* __restrict__ b2, const float* __restrict__ mix,
    float* __restrict__ out, float* __restrict__ P1) {
  constexpr int K = 4096, KH = 2048, NT = KH / 32;  // 64
  __shared__ alignas(16) u16 smem[20480];  // sA 3x4096 @0 | sB 2x4096 @12288
  const int tid = threadIdx.x;
  const int logical = (blockIdx.x & 7) * 128 + (blockIdx.x >> 3);
  const int xcd_chunk = logical >> 7;          // 0..7
  const int i_ = logical & 127;
  const int kc = i_ >> 6;                      // 0/1 (both halves same XCD)
  const int bn = i_ & 7;
  const int bm = xcd_chunk * 8 + ((i_ >> 3) & 7);
  const int m0 = bm * 128, n0 = bn * 128;
  const size_t kbase = (size_t)kc * KH;
  const int wid = tid >> 6, lane = tid & 63;
  const int wm = (wid >> 1) * 64, wn = (wid & 1) * 64;
  const int fr = lane & 15, fk = lane >> 4;

  const int c0_ = tid, c1_ = tid + 256;
  const int r0_ = c0_ >> 2, s0_ = ((c0_ & 3) ^ ((r0_ >> 1) & 3)) * 8;
  const int r1_ = c1_ >> 2, s1_ = ((c1_ & 3) ^ ((r1_ >> 1) & 3)) * 8;

#define STG2_A(v)                                                                     \
  do {                                                                                \
    const int kb = (v) * 32;                                                          \
    u16* dA = smem + ((v) % 3) * 4096;                                                \
    gload16(&Hm[(size_t)(m0 + r0_) * K + kbase + kb + s0_], &dA[c0_ * 8]);            \
    gload16(&Hm[(size_t)(m0 + r1_) * K + kbase + kb + s1_], &dA[c1_ * 8]);            \
  } while (0)
#define STG2_B(v)                                                                     \
  do {                                                                                \
    const int kb = (v) * 32;                                                          \
    u16* dB = smem + 12288 + ((v) & 1) * 4096;                                        \
    gload16(&W2T[(size_t)(n0 + r0_) * K + kbase + kb + s0_], &dB[c0_ * 8]);           \
    gload16(&W2T[(size_t)(n0 + r1_) * K + kbase + kb + s1_], &dB[c1_ * 8]);           \
  } while (0)

  f32x4 acc[4][4];
#pragma unroll
  for (int i = 0; i < 4; ++i)
#pragma unroll
    for (int j = 0; j < 4; ++j) acc[i][j] = (f32x4)0.0f;

  const int slot_ = (fk ^ ((fr >> 1) & 3)) * 8;

  // prologue (issue order): B0, A0, A1
  STG2_B(0); STG2_A(0); STG2_A(1);

  for (int u = 0; u < NT; ++u) {
    if (u + 1 < NT) { VMC(2); } else { VMC(0); }
    BARX();
    if (u + 1 < NT) STG2_B(u + 1);
    if (u + 2 < NT) STG2_A(u + 2);
    __builtin_amdgcn_sched_barrier(0);
    const u16* A_ = smem + (u % 3) * 4096;
    const u16* B_ = smem + 12288 + (u & 1) * 4096;
    bf16x8 a_[4], b_[4];
#pragma unroll
    for (int i = 0; i < 4; ++i) {
      a_[i] = *(const bf16x8*)&A_[(wm + i * 16 + fr) * 32 + slot_];
      b_[i] = *(const bf16x8*)&B_[(wn + i * 16 + fr) * 32 + slot_];
    }
    __builtin_amdgcn_s_setprio(1);
#pragma unroll
    for (int i = 0; i < 4; ++i)
#pragma unroll
      for (int j = 0; j < 4; ++j)
        acc[i][j] = MFMA(a_[i], b_[j], acc[i][j]);
    __builtin_amdgcn_s_setprio(0);
  }
#undef STG2_A
#undef STG2_B

  // ---- epilogue: two 64-row passes through LDS, full-line stores ----
  float* dst = (kc == 0) ? out : P1;
  float* os = (float*)smem;                 // [64][128] f32 (32 KB)
  const int myhalf = wid >> 1;              // waves 0,1 -> rows 0..63; 2,3 -> 64..127
#pragma unroll
  for (int half = 0; half < 2; ++half) {
    BARX();
    if (myhalf == half) {
#pragma unroll
      for (int nf = 0; nf < 4; ++nf) {
        int col_l = wn + nf * 16 + fr;
        float bc[8];
        if (kc == 0) {
#pragma unroll
          for (int l = 0; l < 8; ++l) bc[l] = b2[l * 1024 + n0 + col_l];
        }
#pragma unroll
        for (int mf = 0; mf < 4; ++mf)
#pragma unroll
          for (int r = 0; r < 4; ++r) {
            int row_lh = mf * 16 + fk * 4 + r;   // 0..63 within half
            float v = acc[mf][nf][r];
            if (kc == 0) {
              const float* mr = mix + (size_t)(m0 + half * 64 + row_lh) * 8;
              float bias = 0.f;
#pragma unroll
              for (int l = 0; l < 8; ++l) bias = fmaf(mr[l], bc[l], bias);
              v += bias;
            }
            os[row_lh * 128 + col_l] = v;
          }
      }
    }
    BARX();
#pragma unroll
    for (int j = 0; j < 8; ++j) {
      int idx = j * 256 + tid;      // 2048 chunks of 16B
      int row_lh = idx >> 5;        // 32 chunks per row
      int cc = (idx & 31) * 4;
      *(float4*)&dst[(size_t)(m0 + half * 64 + row_lh) * 1024 + n0 + cc] =
          *(const float4*)&os[row_lh * 128 + cc];
    }
  }
}

// ---------------- out += P1 (float4, 96 MB traffic) ----------------
__global__ void k_add(float* __restrict__ out, const float* __restrict__ P1) {
  size_t i = (size_t)blockIdx.x * 256 + threadIdx.x;
  float4 a = ((const float4*)out)[i];
  float4 b = ((const float4*)P1)[i];
  a.x += b.x; a.y += b.y; a.z += b.z; a.w += b.w;
  ((float4*)out)[i] = a;
}

extern "C" void kernel_launch(void* const* d_in, const int* in_sizes, int n_in,
                              void* d_out, int out_size, void* d_ws, size_t ws_size,
                              hipStream_t stream) {
  const float* x   = (const float*)d_in[0];
  const float* nk  = (const float*)d_in[1];
  const float* nb  = (const float*)d_in[2];
  const float* w1a = (const float*)d_in[3];
  const float* w1b = (const float*)d_in[4];
  const float* b1a = (const float*)d_in[5];
  const float* b1b = (const float*)d_in[6];
  const float* w2  = (const float*)d_in[7];
  const float* b2  = (const float*)d_in[8];
  float* out = (float*)d_out;

  char* ws = (char*)d_ws;
  // layout: mixture | Xbf | W1aT | W1bT | W2T | H   (~109.3 MB)
  // After gemm1, Xb+WaT+WbT (32.75 MB) are dead; P1 (32 MB) reuses
  // [262144, 262144+33554432) which ends exactly at W2T's start.
  float* mix = (float*)ws;                                   // 262144 B
  u16* Xb  = (u16*)(ws + 262144);                            // 16777216 B
  u16* WaT = (u16*)(ws + 262144 + 16777216);                 // 8388608 B
  u16* WbT = (u16*)(ws + 262144 + 16777216 + 8388608);       // 8388608 B
  u16* W2T = (u16*)(ws + 262144 + 16777216 + 2 * 8388608);   // 8388608 B
  u16* Hs  = (u16*)(ws + 262144 + 16777216 + 3 * 8388608);   // 67108864 B
  float* P1 = (float*)(ws + 262144);                         // 33554432 B (reclaim)

  k_gatecast<<<2048, 256, 0, stream>>>(x, nk, nb, mix, Xb);
  // merged: w1a/w1b -> WaT/WbT and w2 -> W2T in one launch (12288 blocks)
  k_transpose_all<<<12288, 256, 0, stream>>>(w1a, w1b, w2, WaT, WbT, W2T);
  k_glu_gemm<<<2048, 256, 0, stream>>>(Xb, WaT, WbT, b1a, b1b, mix, Hs);
  k_gemm2s<<<1024, 256, 0, stream>>>(Hs, W2T, b2, mix, out, P1);
  k_add<<<8192, 256, 0, stream>>>(out, P1);
}